// Round 11
// baseline (282.480 us; speedup 1.0000x reference)
//
#include <hip/hip_runtime.h>
#include <hip/hip_fp16.h>

#define NN 50000
#define NE 800000
#define NBUCK 392          // buckets of 128 node-ids (7-bit local bins)

__device__ __forceinline__ float sigm(float v) { return 1.0f / (1.0f + __expf(-v)); }

// ===========================================================================
// Sort-based CSR construction — R8/R10-proven structure. R11: scatter passes
// take 4096 edges/block (runs ~10.4 rec ≈ 83B -> fewer partial-line writes,
// half the cursor atomics).
// ===========================================================================

// ---- stage 0: global per-bucket counts for dst (A) and src (B) ----
__global__ void sort_count(const int* __restrict__ ei,
                           int* __restrict__ cntA, int* __restrict__ cntB)
{
    __shared__ int hA[NBUCK], hB[NBUCK];
    int t = threadIdx.x;
    for (int i = t; i < NBUCK; i += 256) { hA[i] = 0; hB[i] = 0; }
    __syncthreads();
    int base = blockIdx.x * 4096;
#pragma unroll
    for (int r = 0; r < 16; ++r) {
        int idx = base + r * 256 + t;
        if (idx < NE) {
            int s = ei[idx], d = ei[NE + idx];
            atomicAdd(&hB[s >> 7], 1);
            atomicAdd(&hA[d >> 7], 1);
        }
    }
    __syncthreads();
    for (int i = t; i < NBUCK; i += 256) {
        if (hA[i]) atomicAdd(&cntA[i], hA[i]);
        if (hB[i]) atomicAdd(&cntB[i], hB[i]);
    }
}

// ---- exclusive scan of the 392 bucket counts (A and B), init cursors ----
__global__ void sort_scan(const int* __restrict__ cntA, const int* __restrict__ cntB,
                          int* __restrict__ baseA, int* __restrict__ baseB,
                          int* __restrict__ curA,  int* __restrict__ curB)
{
    __shared__ int a[512], b[512];
    int t = threadIdx.x;
    a[t] = (t < NBUCK) ? cntA[t] : 0;
    b[t] = (t < NBUCK) ? cntB[t] : 0;
    __syncthreads();
#pragma unroll
    for (int dd = 1; dd < 512; dd <<= 1) {
        int av = (t >= dd) ? a[t - dd] : 0;
        int bv = (t >= dd) ? b[t - dd] : 0;
        __syncthreads();
        a[t] += av; b[t] += bv;
        __syncthreads();
    }
    int exA = (t > 0) ? a[t - 1] : 0;
    int exB = (t > 0) ? b[t - 1] : 0;
    if (t < NBUCK) { baseA[t] = exA; curA[t] = exA; baseB[t] = exB; curB[t] = exB; }
    if (t == 511)  { baseA[NBUCK] = a[511]; baseB[NBUCK] = b[511]; }  // == NE
}

// ---- stage 1A: scatter {dlow:7|s:16|e:20} u64 into dst-buckets ----
__global__ __launch_bounds__(256) void sort_scatterA(const int* __restrict__ ei,
                                                     int* __restrict__ curA,
                                                     unsigned long long* __restrict__ recA)
{
    __shared__ int lcnt[NBUCK];
    __shared__ int lofs[NBUCK];
    int t = threadIdx.x;
    for (int i = t; i < NBUCK; i += 256) lcnt[i] = 0;
    __syncthreads();
    int base = blockIdx.x * 4096;
#pragma unroll
    for (int r = 0; r < 16; ++r) {
        int e = base + r * 256 + t;
        if (e < NE) atomicAdd(&lcnt[ei[NE + e] >> 7], 1);
    }
    __syncthreads();
    for (int i = t; i < NBUCK; i += 256)
        lofs[i] = lcnt[i] ? atomicAdd(&curA[i], lcnt[i]) : 0;
    __syncthreads();
#pragma unroll
    for (int r = 0; r < 16; ++r) {
        int e = base + r * 256 + t;
        if (e < NE) {
            int s = ei[e], d = ei[NE + e];
            int p = atomicAdd(&lofs[d >> 7], 1);
            recA[p] = ((unsigned long long)(unsigned)(d & 127) << 36)
                    | ((unsigned long long)(unsigned)s << 20)
                    | (unsigned long long)(unsigned)e;
        }
    }
}

// ---- stage 2A+1B fused: per-dst-bucket 128-bin counting sort -> dp,
//      off_all[d]; AND direct scatter {slow:7|dp:20|e:20} into src-buckets ----
__global__ __launch_bounds__(256) void sort_localAB(const unsigned long long* __restrict__ recA,
                                                    const int* __restrict__ baseA,
                                                    int* __restrict__ off_all,
                                                    int* __restrict__ curB,
                                                    unsigned long long* __restrict__ recB)
{
    __shared__ int c[128];
    __shared__ int live[128];
    __shared__ int lcnt[NBUCK];
    __shared__ int lofs[NBUCK];
    int t = threadIdx.x;
    int b = blockIdx.x;
    int lo = baseA[b], hi = baseA[b + 1];
    if (t < 128) c[t] = 0;
    for (int i = t; i < NBUCK; i += 256) lcnt[i] = 0;
    __syncthreads();
    for (int i = lo + t; i < hi; i += 256) {
        unsigned long long rec = recA[i];
        atomicAdd(&c[(int)(rec >> 36) & 127], 1);       // d-bin
        atomicAdd(&lcnt[(int)(rec >> 27) & 511], 1);    // s>>7 bucket
    }
    __syncthreads();
#pragma unroll
    for (int dd = 1; dd < 128; dd <<= 1) {
        int v = (t >= dd && t < 128) ? c[t - dd] : 0;
        __syncthreads();
        if (t < 128) c[t] += v;
        __syncthreads();
    }
    if (t < 128) {
        int ex = (t > 0) ? c[t - 1] : 0;      // exclusive within-bucket prefix
        int d = (b << 7) + t;
        if (d <= NN) off_all[d] = lo + ex;    // d==NN -> b=390,t=80 -> NE
        live[t] = lo + ex;
    }
    __syncthreads();
    for (int i = t; i < NBUCK; i += 256)
        lofs[i] = lcnt[i] ? atomicAdd(&curB[i], lcnt[i]) : 0;
    __syncthreads();
    for (int i = lo + t; i < hi; i += 256) {
        unsigned long long rec = recA[i];
        int dp = atomicAdd(&live[(int)(rec >> 36) & 127], 1);
        int s  = (int)((rec >> 20) & 0xFFFFu);
        int p  = atomicAdd(&lofs[s >> 7], 1);
        recB[p] = ((unsigned long long)(unsigned)(s & 127) << 40)
                | ((unsigned long long)(unsigned)dp << 20)
                | (rec & 0xFFFFFull);                    // e
    }
}

// ---- stage 2B: per-bucket sort by s&127 -> sperm32 + ea_perm + src offs ----
__global__ __launch_bounds__(256) void sort_localB(const unsigned long long* __restrict__ recB,
                                                   const int* __restrict__ baseB,
                                                   const float4* __restrict__ ea4,
                                                   int* __restrict__ off_all,
                                                   unsigned* __restrict__ sperm32,
                                                   float4* __restrict__ ea_perm)
{
    __shared__ int c[128];
    __shared__ int live[128];
    int t = threadIdx.x;
    int b = blockIdx.x;
    int lo = baseB[b], hi = baseB[b + 1];
    if (t < 128) c[t] = 0;
    __syncthreads();
    for (int i = lo + t; i < hi; i += 256)
        atomicAdd(&c[(int)(recB[i] >> 40) & 127], 1);
    __syncthreads();
#pragma unroll
    for (int dd = 1; dd < 128; dd <<= 1) {
        int v = (t >= dd && t < 128) ? c[t - dd] : 0;
        __syncthreads();
        if (t < 128) c[t] += v;
        __syncthreads();
    }
    if (t < 128) {
        int ex = (t > 0) ? c[t - 1] : 0;
        int s = (b << 7) + t;
        if (s <= NN) off_all[NN + s] = NE + lo + ex;   // old off_all layout
        live[t] = lo + ex;
    }
    __syncthreads();
    for (int i = lo + t; i < hi; i += 256) {
        unsigned long long rec = recB[i];
        int k = (int)(rec >> 40) & 127;
        int pos = atomicAdd(&live[k], 1);
        unsigned sl = (unsigned)(k & 15);              // ((b<<7)+k)&15 == k&15
        unsigned dp = (unsigned)((rec >> 20) & 0xFFFFFu);
        sperm32[pos] = (sl << 20) | dp;
        ea_perm[pos] = ea4[rec & 0xFFFFFull];          // THE random gather, once
    }
}

// ===========================================================================
// edge_fusedG<DIN>: R9-proven phase-2 (reg-pack, barrier-free, random 32B row
// store). R11 delta: phase-1 w2 staged in TWO halves into one 8.7KB buffer,
// partial G kept in registers between halves. Block LDS 38.9K -> ~30K
// (DIN=16) / ~25K (DIN=8) -> 3-4 blocks/CU instead of 2.
// ===========================================================================
template<int DIN>
__global__ __launch_bounds__(256) void edge_fusedG(
        const float* __restrict__ xin,        // [NN][DIN]
        const unsigned* __restrict__ sperm32, // [NE] {sl:4|dp:20} src-sorted
        const float4* __restrict__ ea_perm,   // [NE] src-sorted edge attrs
        const float* __restrict__ eW1,        // [4][16]
        const float* __restrict__ eb1,        // [16]
        const float* __restrict__ eW2,        // [16][DIN*16]
        const float* __restrict__ eb2,        // [DIN*16]
        const int*   __restrict__ off_all,    // src CSR at off_all[NN+s]
        __half* __restrict__ msgbuf)          // [NE][16] fp16 dst-sorted rows
{
    constexpr int H = DIN / 2;
    __shared__ __align__(16) float4 w2h[4 * H * 17];    // [(ob*H+i)*17+k] half
    __shared__ __align__(16) float4 G4[16 * 69];        // [sl*69 + ob*17 + k]
    __shared__ __align__(16) float4 xbL[16 * 5];        // [sl*5 + ob] (pad 5)
    __shared__ __align__(16) float  xL[16 * DIN];
    __shared__ __align__(16) float  b2L[DIN * 16];
    __shared__ __align__(16) float4 w1t[16];
    __shared__ __align__(16) float  b1s[16];

    int tid = threadIdx.x;
    int nb  = blockIdx.x * 16;                // first src node of block
    if (tid < 16) {
        w1t[tid] = make_float4(eW1[tid], eW1[16 + tid], eW1[32 + tid], eW1[48 + tid]);
        b1s[tid] = eb1[tid];
    }
    for (int t = tid; t < DIN * 16; t += 256) b2L[t] = eb2[t];
    for (int t = tid; t < 16 * DIN; t += 256) xL[t] = xin[(size_t)nb * DIN + t];

    // ---- phase 1: G + xb in two w2-halves; thread (nl, k) ----
    {
        int nl = tid >> 4, k = tid & 15;
        float4 a4[4];
#pragma unroll
        for (int ob = 0; ob < 4; ++ob) a4[ob] = make_float4(0.f, 0.f, 0.f, 0.f);

#pragma unroll
        for (int step = 0; step < 2; ++step) {
            __syncthreads();   // prev readers done (and first: xL/b2L staged)
            {   // stage half: w2h[(ob*H+i)*17+k].c = eW2[kk][(step*H+i)*16+ob*4+c]
                float* w2f = (float*)w2h;
                for (int t = tid; t < 16 * H * 16; t += 256) {
                    int kk = t / (H * 16);
                    int rem = t - kk * (H * 16);
                    int i = rem >> 4, o = rem & 15;
                    w2f[((((o >> 2) * H + i) * 17) + kk) * 4 + (o & 3)] =
                        eW2[kk * (DIN * 16) + (step * H + i) * 16 + o];
                }
            }
            __syncthreads();
            const float* xrow = xL + nl * DIN + step * H;
#pragma unroll
            for (int ob = 0; ob < 4; ++ob) {
#pragma unroll
                for (int i = 0; i < H; ++i) {
                    float4 w = w2h[(ob * H + i) * 17 + k];
                    a4[ob].x += xrow[i] * w.x; a4[ob].y += xrow[i] * w.y;
                    a4[ob].z += xrow[i] * w.z; a4[ob].w += xrow[i] * w.w;
                }
            }
        }
#pragma unroll
        for (int ob = 0; ob < 4; ++ob) G4[nl * 69 + ob * 17 + k] = a4[ob];

        if (k < 4) {
            int ob = k;
            const float4* b2v = (const float4*)b2L;
            const float* xrow = xL + nl * DIN;
            float4 a = make_float4(0.f, 0.f, 0.f, 0.f);
#pragma unroll
            for (int i = 0; i < DIN; ++i) {
                float4 bb = b2v[i * 4 + ob];
                a.x += xrow[i] * bb.x; a.y += xrow[i] * bb.y;
                a.z += xrow[i] * bb.z; a.w += xrow[i] * bb.w;
            }
            xbL[nl * 5 + ob] = a;
        }
    }
    __syncthreads();

    // ---- phase 2: barrier-free edge loop; reg-pack + 32B random row store ----
    int eBeg = off_all[NN + nb] - NE;
    int eEnd = off_all[NN + nb + 16] - NE;
    for (int pos = eBeg + tid; pos < eEnd; pos += 256) {
        unsigned pk = sperm32[pos];
        int dp = (int)(pk & 0xFFFFFu);
        int sl = (int)(pk >> 20);
        float4 a = ea_perm[pos];

        float h[16];
#pragma unroll
        for (int j = 0; j < 16; ++j) {
            float4 w = w1t[j];
            float p = b1s[j] + a.x * w.x + a.y * w.y + a.z * w.z + a.w * w.w;
            h[j] = p * sigm(p);
        }
        float4 acc[4];
#pragma unroll
        for (int ob = 0; ob < 4; ++ob) acc[ob] = xbL[sl * 5 + ob];
#pragma unroll
        for (int k = 0; k < 16; ++k) {
            float hk = h[k];
#pragma unroll
            for (int ob = 0; ob < 4; ++ob) {
                float4 g = G4[sl * 69 + ob * 17 + k];
                acc[ob].x += hk * g.x; acc[ob].y += hk * g.y;
                acc[ob].z += hk * g.z; acc[ob].w += hk * g.w;
            }
        }
        __half2 h01 = __floats2half2_rn(acc[0].x, acc[0].y);
        __half2 h23 = __floats2half2_rn(acc[0].z, acc[0].w);
        __half2 h45 = __floats2half2_rn(acc[1].x, acc[1].y);
        __half2 h67 = __floats2half2_rn(acc[1].z, acc[1].w);
        __half2 h89 = __floats2half2_rn(acc[2].x, acc[2].y);
        __half2 hAB = __floats2half2_rn(acc[2].z, acc[2].w);
        __half2 hCD = __floats2half2_rn(acc[3].x, acc[3].y);
        __half2 hEF = __floats2half2_rn(acc[3].z, acc[3].w);
        uint4 w0 = make_uint4(*(unsigned*)&h01, *(unsigned*)&h23,
                              *(unsigned*)&h45, *(unsigned*)&h67);
        uint4 w1 = make_uint4(*(unsigned*)&h89, *(unsigned*)&hAB,
                              *(unsigned*)&hCD, *(unsigned*)&hEF);
        uint4* dst = (uint4*)(msgbuf + (size_t)dp * 16);   // random 32B row
        dst[0] = w0;
        dst[1] = w1;
    }
}

// ===========================================================================
// Gather helper (R5-proven): dst-sorted msgbuf -> streaming contiguous reads.
// ===========================================================================
__device__ __forceinline__ float gather_msg16(const __half* __restrict__ msgbuf,
                                              int s0, int e0, int tid)
{
    int half = (tid >> 3) & 1;
    int p    = tid & 7;
    float ax = 0.f, ay = 0.f;
    for (int j = s0 + half; j < e0; j += 2) {
        __half2 hv = *((const __half2*)(msgbuf + (size_t)j * 16) + p);
        float2 f = __half22float2(hv);
        ax += f.x; ay += f.y;
    }
    ax += __shfl_xor(ax, 8, 16);
    ay += __shfl_xor(ay, 8, 16);
    int ch = tid & 15;
    float vx = __shfl(ax, ch >> 1, 16);
    float vy = __shfl(ay, ch >> 1, 16);
    return (ch & 1) ? vy : vx;
}

__global__ __launch_bounds__(256) void gather_L0(
        const float* __restrict__ xin,    // [NN][8]
        const float* __restrict__ root,   // [8][16]
        const float* __restrict__ bias,   // [16]
        const int*   __restrict__ off_all,
        const __half* __restrict__ msgbuf,
        float* __restrict__ x1)           // [NN][16]
{
    __shared__ __align__(16) float rootL[8 * 16];
    __shared__ __align__(16) float biasL[16];
    int tid = threadIdx.x;
    if (tid < 128) rootL[tid] = root[tid];
    if (tid < 16) biasL[tid] = bias[tid];
    __syncthreads();

    int ch = tid & 15;
    int n  = blockIdx.x * 16 + (tid >> 4);
    int s0 = off_all[n], e0 = off_all[n + 1];

    float acc = gather_msg16(msgbuf, s0, e0, tid);
    float v = acc / fmaxf((float)(e0 - s0), 1.0f) + biasL[ch];
#pragma unroll
    for (int i = 0; i < 8; ++i)
        v += xin[(size_t)n * 8 + i] * rootL[i * 16 + ch];
    x1[(size_t)n * 16 + ch] = fmaxf(v, 0.f);
}

__global__ __launch_bounds__(256) void gather_final(
        const float* __restrict__ x1,     // [NN][16]
        const float* __restrict__ root,   // [16][16]
        const float* __restrict__ bias,   // [16]
        const int*   __restrict__ off_all,
        const __half* __restrict__ msgbuf,
        const float* __restrict__ mW1,    // [16][16]
        const float* __restrict__ mb1,    // [16]
        const float* __restrict__ mW2,    // [16]
        const float* __restrict__ mb2,    // [1]
        float* __restrict__ out)          // [NN]
{
    __shared__ __align__(16) float rootL[256];
    __shared__ __align__(16) float biasL[16];
    __shared__ __align__(16) float w1m[256];
    __shared__ __align__(16) float b1m[16];
    __shared__ __align__(16) float w2m[16];
    __shared__ float b2m;
    int tid = threadIdx.x;
    rootL[tid] = root[tid];
    w1m[tid] = mW1[tid];
    if (tid < 16) { biasL[tid] = bias[tid]; b1m[tid] = mb1[tid]; w2m[tid] = mW2[tid]; }
    if (tid == 0) b2m = mb2[0];
    __syncthreads();

    int ch = tid & 15;
    int n  = blockIdx.x * 16 + (tid >> 4);
    int s0 = off_all[n], e0 = off_all[n + 1];

    float acc = gather_msg16(msgbuf, s0, e0, tid);
    float v = acc / fmaxf((float)(e0 - s0), 1.0f) + biasL[ch];
#pragma unroll
    for (int i = 0; i < 16; ++i)
        v += x1[(size_t)n * 16 + i] * rootL[i * 16 + ch];
    v = fmaxf(v, 0.f);

    float z = b1m[ch];
#pragma unroll
    for (int o = 0; o < 16; ++o) {
        float vo = __shfl(v, o, 16);
        z += vo * w1m[o * 16 + ch];
    }
    float ss = z * sigm(z) * w2m[ch];
#pragma unroll
    for (int off = 8; off; off >>= 1) ss += __shfl_xor(ss, off, 16);
    if (ch == 0) out[n] = sigm(ss + b2m);
}

// ===========================================================================
// Host launch
// ===========================================================================
extern "C" void kernel_launch(void* const* d_in, const int* in_sizes, int n_in,
                              void* d_out, int out_size, void* d_ws, size_t ws_size,
                              hipStream_t stream) {
    const float* x     = (const float*)d_in[0];
    const int*   ei    = (const int*)  d_in[1];
    const float* ea    = (const float*)d_in[2];
    const float* eW1_0 = (const float*)d_in[3];
    const float* eb1_0 = (const float*)d_in[4];
    const float* eW2_0 = (const float*)d_in[5];
    const float* eb2_0 = (const float*)d_in[6];
    const float* root0 = (const float*)d_in[7];
    const float* bias0 = (const float*)d_in[8];
    const float* eW1_1 = (const float*)d_in[9];
    const float* eb1_1 = (const float*)d_in[10];
    const float* eW2_1 = (const float*)d_in[11];
    const float* eb2_1 = (const float*)d_in[12];
    const float* root1 = (const float*)d_in[13];
    const float* bias1 = (const float*)d_in[14];
    const float* mW1   = (const float*)d_in[15];
    const float* mb1   = (const float*)d_in[16];
    const float* mW2   = (const float*)d_in[17];
    const float* mb2   = (const float*)d_in[18];
    float* out = (float*)d_out;

    const int GG  = NN / 16;                 // 3125
    const int SBK = (NE + 4095) / 4096;      // 196 blocks for count/scatterA

    // ---- ws layout (4B words), peak 11.30M words = 45.2 MB (proven) ----
    int* W = (int*)d_ws;
    int* off_all = W;                        // [0, 100004)
    int* cntA    = W + 100004;               // 392 (+pad)
    int* cntB    = W + 100400;               // 392
    int* baseA   = W + 100800;               // 400 (393 used)
    int* baseB   = W + 101200;               // 400
    int* curA    = W + 101600;               // 392
    int* curB    = W + 102000;               // 392 -> pad to 102400
    unsigned* sperm32 = (unsigned*)(W + 102400);           // NE u32
    float4* ea_perm   = (float4*)(W + 902400);             // NE float4 (16B-aligned)
    float*  x1        = (float*)(W + 4102400);             // [NN][16]
    __half* msgbuf    = (__half*)(W + 4902400);            // [NE][16] fp16, dst order
    // sort scratch overlaid on msgbuf region (dead before edge kernels run):
    unsigned long long* recA = (unsigned long long*)(W + 4902400); // NE u64
    unsigned long long* recB = (unsigned long long*)(W + 6502400); // NE u64

    hipMemsetAsync(cntA, 0, 2 * 396 * sizeof(int), stream);   // cntA + cntB
    sort_count   <<<SBK,  256, 0, stream>>>(ei, cntA, cntB);
    sort_scan    <<<1,    512, 0, stream>>>(cntA, cntB, baseA, baseB, curA, curB);
    sort_scatterA<<<SBK,  256, 0, stream>>>(ei, curA, recA);
    sort_localAB <<<NBUCK,256, 0, stream>>>(recA, baseA, off_all, curB, recB);
    sort_localB  <<<NBUCK,256, 0, stream>>>(recB, baseB, (const float4*)ea,
                                            off_all, sperm32, ea_perm);

    // ---- layer 0 ----
    edge_fusedG<8><<<GG, 256, 0, stream>>>(x, sperm32, ea_perm, eW1_0, eb1_0,
                                           eW2_0, eb2_0, off_all, msgbuf);
    gather_L0<<<GG, 256, 0, stream>>>(x, root0, bias0, off_all, msgbuf, x1);

    // ---- layer 1 ----
    edge_fusedG<16><<<GG, 256, 0, stream>>>(x1, sperm32, ea_perm, eW1_1, eb1_1,
                                            eW2_1, eb2_1, off_all, msgbuf);
    gather_final<<<GG, 256, 0, stream>>>(x1, root1, bias1, off_all, msgbuf,
                                         mW1, mb1, mW2, mb2, out);
}

// Round 12
// 270.621 us; speedup vs baseline: 1.0438x; 1.0438x over previous
//
#include <hip/hip_runtime.h>
#include <hip/hip_fp16.h>

#define NN 50000
#define NE 800000
#define NBUCK 392          // buckets of 128 node-ids (7-bit local bins)

__device__ __forceinline__ float sigm(float v) { return 1.0f / (1.0f + __expf(-v)); }

// ===========================================================================
// Sort-based CSR construction — R8/R10 structure + R11's 4096-edge scatter
// blocks (runs ~10.4 rec ≈ 83B -> fewer partial-line writes, half the cursor
// atomics; measured ~-15us on the sort section).
// ===========================================================================

// ---- stage 0: global per-bucket counts for dst (A) and src (B) ----
__global__ void sort_count(const int* __restrict__ ei,
                           int* __restrict__ cntA, int* __restrict__ cntB)
{
    __shared__ int hA[NBUCK], hB[NBUCK];
    int t = threadIdx.x;
    for (int i = t; i < NBUCK; i += 256) { hA[i] = 0; hB[i] = 0; }
    __syncthreads();
    int base = blockIdx.x * 4096;
#pragma unroll
    for (int r = 0; r < 16; ++r) {
        int idx = base + r * 256 + t;
        if (idx < NE) {
            int s = ei[idx], d = ei[NE + idx];
            atomicAdd(&hB[s >> 7], 1);
            atomicAdd(&hA[d >> 7], 1);
        }
    }
    __syncthreads();
    for (int i = t; i < NBUCK; i += 256) {
        if (hA[i]) atomicAdd(&cntA[i], hA[i]);
        if (hB[i]) atomicAdd(&cntB[i], hB[i]);
    }
}

// ---- exclusive scan of the 392 bucket counts (A and B), init cursors ----
__global__ void sort_scan(const int* __restrict__ cntA, const int* __restrict__ cntB,
                          int* __restrict__ baseA, int* __restrict__ baseB,
                          int* __restrict__ curA,  int* __restrict__ curB)
{
    __shared__ int a[512], b[512];
    int t = threadIdx.x;
    a[t] = (t < NBUCK) ? cntA[t] : 0;
    b[t] = (t < NBUCK) ? cntB[t] : 0;
    __syncthreads();
#pragma unroll
    for (int dd = 1; dd < 512; dd <<= 1) {
        int av = (t >= dd) ? a[t - dd] : 0;
        int bv = (t >= dd) ? b[t - dd] : 0;
        __syncthreads();
        a[t] += av; b[t] += bv;
        __syncthreads();
    }
    int exA = (t > 0) ? a[t - 1] : 0;
    int exB = (t > 0) ? b[t - 1] : 0;
    if (t < NBUCK) { baseA[t] = exA; curA[t] = exA; baseB[t] = exB; curB[t] = exB; }
    if (t == 511)  { baseA[NBUCK] = a[511]; baseB[NBUCK] = b[511]; }  // == NE
}

// ---- stage 1A: scatter {dlow:7|s:16|e:20} u64 into dst-buckets ----
__global__ __launch_bounds__(256) void sort_scatterA(const int* __restrict__ ei,
                                                     int* __restrict__ curA,
                                                     unsigned long long* __restrict__ recA)
{
    __shared__ int lcnt[NBUCK];
    __shared__ int lofs[NBUCK];
    int t = threadIdx.x;
    for (int i = t; i < NBUCK; i += 256) lcnt[i] = 0;
    __syncthreads();
    int base = blockIdx.x * 4096;
#pragma unroll
    for (int r = 0; r < 16; ++r) {
        int e = base + r * 256 + t;
        if (e < NE) atomicAdd(&lcnt[ei[NE + e] >> 7], 1);
    }
    __syncthreads();
    for (int i = t; i < NBUCK; i += 256)
        lofs[i] = lcnt[i] ? atomicAdd(&curA[i], lcnt[i]) : 0;
    __syncthreads();
#pragma unroll
    for (int r = 0; r < 16; ++r) {
        int e = base + r * 256 + t;
        if (e < NE) {
            int s = ei[e], d = ei[NE + e];
            int p = atomicAdd(&lofs[d >> 7], 1);
            recA[p] = ((unsigned long long)(unsigned)(d & 127) << 36)
                    | ((unsigned long long)(unsigned)s << 20)
                    | (unsigned long long)(unsigned)e;
        }
    }
}

// ---- stage 2A+1B fused: per-dst-bucket 128-bin counting sort -> dp,
//      off_all[d]; AND direct scatter {slow:7|dp:20|e:20} into src-buckets ----
__global__ __launch_bounds__(256) void sort_localAB(const unsigned long long* __restrict__ recA,
                                                    const int* __restrict__ baseA,
                                                    int* __restrict__ off_all,
                                                    int* __restrict__ curB,
                                                    unsigned long long* __restrict__ recB)
{
    __shared__ int c[128];
    __shared__ int live[128];
    __shared__ int lcnt[NBUCK];
    __shared__ int lofs[NBUCK];
    int t = threadIdx.x;
    int b = blockIdx.x;
    int lo = baseA[b], hi = baseA[b + 1];
    if (t < 128) c[t] = 0;
    for (int i = t; i < NBUCK; i += 256) lcnt[i] = 0;
    __syncthreads();
    for (int i = lo + t; i < hi; i += 256) {
        unsigned long long rec = recA[i];
        atomicAdd(&c[(int)(rec >> 36) & 127], 1);       // d-bin
        atomicAdd(&lcnt[(int)(rec >> 27) & 511], 1);    // s>>7 bucket
    }
    __syncthreads();
#pragma unroll
    for (int dd = 1; dd < 128; dd <<= 1) {
        int v = (t >= dd && t < 128) ? c[t - dd] : 0;
        __syncthreads();
        if (t < 128) c[t] += v;
        __syncthreads();
    }
    if (t < 128) {
        int ex = (t > 0) ? c[t - 1] : 0;      // exclusive within-bucket prefix
        int d = (b << 7) + t;
        if (d <= NN) off_all[d] = lo + ex;    // d==NN -> b=390,t=80 -> NE
        live[t] = lo + ex;
    }
    __syncthreads();
    for (int i = t; i < NBUCK; i += 256)
        lofs[i] = lcnt[i] ? atomicAdd(&curB[i], lcnt[i]) : 0;
    __syncthreads();
    for (int i = lo + t; i < hi; i += 256) {
        unsigned long long rec = recA[i];
        int dp = atomicAdd(&live[(int)(rec >> 36) & 127], 1);
        int s  = (int)((rec >> 20) & 0xFFFFu);
        int p  = atomicAdd(&lofs[s >> 7], 1);
        recB[p] = ((unsigned long long)(unsigned)(s & 127) << 40)
                | ((unsigned long long)(unsigned)dp << 20)
                | (rec & 0xFFFFFull);                    // e
    }
}

// ---- stage 2B: per-bucket sort by s&127 -> sperm32 + ea_perm + src offs ----
__global__ __launch_bounds__(256) void sort_localB(const unsigned long long* __restrict__ recB,
                                                   const int* __restrict__ baseB,
                                                   const float4* __restrict__ ea4,
                                                   int* __restrict__ off_all,
                                                   unsigned* __restrict__ sperm32,
                                                   float4* __restrict__ ea_perm)
{
    __shared__ int c[128];
    __shared__ int live[128];
    int t = threadIdx.x;
    int b = blockIdx.x;
    int lo = baseB[b], hi = baseB[b + 1];
    if (t < 128) c[t] = 0;
    __syncthreads();
    for (int i = lo + t; i < hi; i += 256)
        atomicAdd(&c[(int)(recB[i] >> 40) & 127], 1);
    __syncthreads();
#pragma unroll
    for (int dd = 1; dd < 128; dd <<= 1) {
        int v = (t >= dd && t < 128) ? c[t - dd] : 0;
        __syncthreads();
        if (t < 128) c[t] += v;
        __syncthreads();
    }
    if (t < 128) {
        int ex = (t > 0) ? c[t - 1] : 0;
        int s = (b << 7) + t;
        if (s <= NN) off_all[NN + s] = NE + lo + ex;   // old off_all layout
        live[t] = lo + ex;
    }
    __syncthreads();
    for (int i = lo + t; i < hi; i += 256) {
        unsigned long long rec = recB[i];
        int k = (int)(rec >> 40) & 127;
        int pos = atomicAdd(&live[k], 1);
        unsigned sl = (unsigned)(k & 15);              // ((b<<7)+k)&15 == k&15
        unsigned dp = (unsigned)((rec >> 20) & 0xFFFFFu);
        sperm32[pos] = (sl << 20) | dp;
        ea_perm[pos] = ea4[rec & 0xFFFFFull];          // THE random gather, once
    }
}

// ===========================================================================
// edge_fusedG<DIN>: R10-proven verbatim (45.2us, 64 VGPR, 38.9KB LDS).
// Reg-pack barrier-free phase 2: each thread owns its 16-ch row, 8x half2
// in regs, two 16B stores to the random dp row (same 32B sector).
// Phase 1: single-pass pad-17 LDS w2 staging.
// ===========================================================================
template<int DIN>
__global__ __launch_bounds__(256) void edge_fusedG(
        const float* __restrict__ xin,        // [NN][DIN]
        const unsigned* __restrict__ sperm32, // [NE] {sl:4|dp:20} src-sorted
        const float4* __restrict__ ea_perm,   // [NE] src-sorted edge attrs
        const float* __restrict__ eW1,        // [4][16]
        const float* __restrict__ eb1,        // [16]
        const float* __restrict__ eW2,        // [16][DIN*16]
        const float* __restrict__ eb2,        // [DIN*16]
        const int*   __restrict__ off_all,    // src CSR at off_all[NN+s]
        __half* __restrict__ msgbuf)          // [NE][16] fp16 dst-sorted rows
{
    __shared__ __align__(16) float4 w2L4[4 * DIN * 17]; // [(ob*DIN+i)*17+k]
    __shared__ __align__(16) float4 G4[16 * 69];        // [sl*69 + ob*17 + k]
    __shared__ __align__(16) float4 xbL[16 * 5];        // [sl*5 + ob] (pad 5)
    __shared__ __align__(16) float  xL[16 * DIN];
    __shared__ __align__(16) float  b2L[DIN * 16];
    __shared__ __align__(16) float4 w1t[16];
    __shared__ __align__(16) float  b1s[16];

    int tid = threadIdx.x;
    int nb  = blockIdx.x * 16;                // first src node of block
    if (tid < 16) {
        w1t[tid] = make_float4(eW1[tid], eW1[16 + tid], eW1[32 + tid], eW1[48 + tid]);
        b1s[tid] = eb1[tid];
    }
    {   // w2L4[(ob*DIN+i)*17 + k].c = eW2[k][i*16 + ob*4 + c]
        float* w2f = (float*)w2L4;
        for (int t = tid; t < 16 * DIN * 16; t += 256) {
            int k = t / (DIN * 16);
            int rem = t - k * DIN * 16;
            int i = rem >> 4, o = rem & 15;
            w2f[((((o >> 2) * DIN + i) * 17) + k) * 4 + (o & 3)] = eW2[t];
        }
    }
    for (int t = tid; t < DIN * 16; t += 256) b2L[t] = eb2[t];
    for (int t = tid; t < 16 * DIN; t += 256) xL[t] = xin[(size_t)nb * DIN + t];
    __syncthreads();

    // ---- phase 1: G + xb for 16 local nodes; thread (nl, k) ----
    {
        int nl = tid >> 4, k = tid & 15;
        const float* xrow = xL + nl * DIN;
#pragma unroll
        for (int ob = 0; ob < 4; ++ob) {
            float4 a4 = make_float4(0.f, 0.f, 0.f, 0.f);
#pragma unroll
            for (int i = 0; i < DIN; ++i) {
                float4 w = w2L4[(ob * DIN + i) * 17 + k];
                a4.x += xrow[i] * w.x; a4.y += xrow[i] * w.y;
                a4.z += xrow[i] * w.z; a4.w += xrow[i] * w.w;
            }
            G4[nl * 69 + ob * 17 + k] = a4;
        }
        if (k < 4) {
            int ob = k;
            const float4* b2v = (const float4*)b2L;
            float4 a4 = make_float4(0.f, 0.f, 0.f, 0.f);
#pragma unroll
            for (int i = 0; i < DIN; ++i) {
                float4 b = b2v[i * 4 + ob];
                a4.x += xrow[i] * b.x; a4.y += xrow[i] * b.y;
                a4.z += xrow[i] * b.z; a4.w += xrow[i] * b.w;
            }
            xbL[nl * 5 + ob] = a4;
        }
    }
    __syncthreads();

    // ---- phase 2: barrier-free edge loop; reg-pack + 32B random row store ----
    int eBeg = off_all[NN + nb] - NE;
    int eEnd = off_all[NN + nb + 16] - NE;
    for (int pos = eBeg + tid; pos < eEnd; pos += 256) {
        unsigned pk = sperm32[pos];
        int dp = (int)(pk & 0xFFFFFu);
        int sl = (int)(pk >> 20);
        float4 a = ea_perm[pos];

        float h[16];
#pragma unroll
        for (int j = 0; j < 16; ++j) {
            float4 w = w1t[j];
            float p = b1s[j] + a.x * w.x + a.y * w.y + a.z * w.z + a.w * w.w;
            h[j] = p * sigm(p);
        }
        float4 acc[4];
#pragma unroll
        for (int ob = 0; ob < 4; ++ob) acc[ob] = xbL[sl * 5 + ob];
#pragma unroll
        for (int k = 0; k < 16; ++k) {
            float hk = h[k];
#pragma unroll
            for (int ob = 0; ob < 4; ++ob) {
                float4 g = G4[sl * 69 + ob * 17 + k];
                acc[ob].x += hk * g.x; acc[ob].y += hk * g.y;
                acc[ob].z += hk * g.z; acc[ob].w += hk * g.w;
            }
        }
        __half2 h01 = __floats2half2_rn(acc[0].x, acc[0].y);
        __half2 h23 = __floats2half2_rn(acc[0].z, acc[0].w);
        __half2 h45 = __floats2half2_rn(acc[1].x, acc[1].y);
        __half2 h67 = __floats2half2_rn(acc[1].z, acc[1].w);
        __half2 h89 = __floats2half2_rn(acc[2].x, acc[2].y);
        __half2 hAB = __floats2half2_rn(acc[2].z, acc[2].w);
        __half2 hCD = __floats2half2_rn(acc[3].x, acc[3].y);
        __half2 hEF = __floats2half2_rn(acc[3].z, acc[3].w);
        uint4 w0 = make_uint4(*(unsigned*)&h01, *(unsigned*)&h23,
                              *(unsigned*)&h45, *(unsigned*)&h67);
        uint4 w1 = make_uint4(*(unsigned*)&h89, *(unsigned*)&hAB,
                              *(unsigned*)&hCD, *(unsigned*)&hEF);
        uint4* dst = (uint4*)(msgbuf + (size_t)dp * 16);   // random 32B row
        dst[0] = w0;
        dst[1] = w1;
    }
}

// ===========================================================================
// Gather helper (R5-proven): dst-sorted msgbuf -> streaming contiguous reads.
// ===========================================================================
__device__ __forceinline__ float gather_msg16(const __half* __restrict__ msgbuf,
                                              int s0, int e0, int tid)
{
    int half = (tid >> 3) & 1;
    int p    = tid & 7;
    float ax = 0.f, ay = 0.f;
    for (int j = s0 + half; j < e0; j += 2) {
        __half2 hv = *((const __half2*)(msgbuf + (size_t)j * 16) + p);
        float2 f = __half22float2(hv);
        ax += f.x; ay += f.y;
    }
    ax += __shfl_xor(ax, 8, 16);
    ay += __shfl_xor(ay, 8, 16);
    int ch = tid & 15;
    float vx = __shfl(ax, ch >> 1, 16);
    float vy = __shfl(ay, ch >> 1, 16);
    return (ch & 1) ? vy : vx;
}

__global__ __launch_bounds__(256) void gather_L0(
        const float* __restrict__ xin,    // [NN][8]
        const float* __restrict__ root,   // [8][16]
        const float* __restrict__ bias,   // [16]
        const int*   __restrict__ off_all,
        const __half* __restrict__ msgbuf,
        float* __restrict__ x1)           // [NN][16]
{
    __shared__ __align__(16) float rootL[8 * 16];
    __shared__ __align__(16) float biasL[16];
    int tid = threadIdx.x;
    if (tid < 128) rootL[tid] = root[tid];
    if (tid < 16) biasL[tid] = bias[tid];
    __syncthreads();

    int ch = tid & 15;
    int n  = blockIdx.x * 16 + (tid >> 4);
    int s0 = off_all[n], e0 = off_all[n + 1];

    float acc = gather_msg16(msgbuf, s0, e0, tid);
    float v = acc / fmaxf((float)(e0 - s0), 1.0f) + biasL[ch];
#pragma unroll
    for (int i = 0; i < 8; ++i)
        v += xin[(size_t)n * 8 + i] * rootL[i * 16 + ch];
    x1[(size_t)n * 16 + ch] = fmaxf(v, 0.f);
}

__global__ __launch_bounds__(256) void gather_final(
        const float* __restrict__ x1,     // [NN][16]
        const float* __restrict__ root,   // [16][16]
        const float* __restrict__ bias,   // [16]
        const int*   __restrict__ off_all,
        const __half* __restrict__ msgbuf,
        const float* __restrict__ mW1,    // [16][16]
        const float* __restrict__ mb1,    // [16]
        const float* __restrict__ mW2,    // [16]
        const float* __restrict__ mb2,    // [1]
        float* __restrict__ out)          // [NN]
{
    __shared__ __align__(16) float rootL[256];
    __shared__ __align__(16) float biasL[16];
    __shared__ __align__(16) float w1m[256];
    __shared__ __align__(16) float b1m[16];
    __shared__ __align__(16) float w2m[16];
    __shared__ float b2m;
    int tid = threadIdx.x;
    rootL[tid] = root[tid];
    w1m[tid] = mW1[tid];
    if (tid < 16) { biasL[tid] = bias[tid]; b1m[tid] = mb1[tid]; w2m[tid] = mW2[tid]; }
    if (tid == 0) b2m = mb2[0];
    __syncthreads();

    int ch = tid & 15;
    int n  = blockIdx.x * 16 + (tid >> 4);
    int s0 = off_all[n], e0 = off_all[n + 1];

    float acc = gather_msg16(msgbuf, s0, e0, tid);
    float v = acc / fmaxf((float)(e0 - s0), 1.0f) + biasL[ch];
#pragma unroll
    for (int i = 0; i < 16; ++i)
        v += x1[(size_t)n * 16 + i] * rootL[i * 16 + ch];
    v = fmaxf(v, 0.f);

    float z = b1m[ch];
#pragma unroll
    for (int o = 0; o < 16; ++o) {
        float vo = __shfl(v, o, 16);
        z += vo * w1m[o * 16 + ch];
    }
    float ss = z * sigm(z) * w2m[ch];
#pragma unroll
    for (int off = 8; off; off >>= 1) ss += __shfl_xor(ss, off, 16);
    if (ch == 0) out[n] = sigm(ss + b2m);
}

// ===========================================================================
// Host launch
// ===========================================================================
extern "C" void kernel_launch(void* const* d_in, const int* in_sizes, int n_in,
                              void* d_out, int out_size, void* d_ws, size_t ws_size,
                              hipStream_t stream) {
    const float* x     = (const float*)d_in[0];
    const int*   ei    = (const int*)  d_in[1];
    const float* ea    = (const float*)d_in[2];
    const float* eW1_0 = (const float*)d_in[3];
    const float* eb1_0 = (const float*)d_in[4];
    const float* eW2_0 = (const float*)d_in[5];
    const float* eb2_0 = (const float*)d_in[6];
    const float* root0 = (const float*)d_in[7];
    const float* bias0 = (const float*)d_in[8];
    const float* eW1_1 = (const float*)d_in[9];
    const float* eb1_1 = (const float*)d_in[10];
    const float* eW2_1 = (const float*)d_in[11];
    const float* eb2_1 = (const float*)d_in[12];
    const float* root1 = (const float*)d_in[13];
    const float* bias1 = (const float*)d_in[14];
    const float* mW1   = (const float*)d_in[15];
    const float* mb1   = (const float*)d_in[16];
    const float* mW2   = (const float*)d_in[17];
    const float* mb2   = (const float*)d_in[18];
    float* out = (float*)d_out;

    const int GG  = NN / 16;                 // 3125
    const int SBK = (NE + 4095) / 4096;      // 196 blocks for count/scatterA

    // ---- ws layout (4B words), peak 11.30M words = 45.2 MB (proven) ----
    int* W = (int*)d_ws;
    int* off_all = W;                        // [0, 100004)
    int* cntA    = W + 100004;               // 392 (+pad)
    int* cntB    = W + 100400;               // 392
    int* baseA   = W + 100800;               // 400 (393 used)
    int* baseB   = W + 101200;               // 400
    int* curA    = W + 101600;               // 392
    int* curB    = W + 102000;               // 392 -> pad to 102400
    unsigned* sperm32 = (unsigned*)(W + 102400);           // NE u32
    float4* ea_perm   = (float4*)(W + 902400);             // NE float4 (16B-aligned)
    float*  x1        = (float*)(W + 4102400);             // [NN][16]
    __half* msgbuf    = (__half*)(W + 4902400);            // [NE][16] fp16, dst order
    // sort scratch overlaid on msgbuf region (dead before edge kernels run):
    unsigned long long* recA = (unsigned long long*)(W + 4902400); // NE u64
    unsigned long long* recB = (unsigned long long*)(W + 6502400); // NE u64

    hipMemsetAsync(cntA, 0, 2 * 396 * sizeof(int), stream);   // cntA + cntB
    sort_count   <<<SBK,  256, 0, stream>>>(ei, cntA, cntB);
    sort_scan    <<<1,    512, 0, stream>>>(cntA, cntB, baseA, baseB, curA, curB);
    sort_scatterA<<<SBK,  256, 0, stream>>>(ei, curA, recA);
    sort_localAB <<<NBUCK,256, 0, stream>>>(recA, baseA, off_all, curB, recB);
    sort_localB  <<<NBUCK,256, 0, stream>>>(recB, baseB, (const float4*)ea,
                                            off_all, sperm32, ea_perm);

    // ---- layer 0 ----
    edge_fusedG<8><<<GG, 256, 0, stream>>>(x, sperm32, ea_perm, eW1_0, eb1_0,
                                           eW2_0, eb2_0, off_all, msgbuf);
    gather_L0<<<GG, 256, 0, stream>>>(x, root0, bias0, off_all, msgbuf, x1);

    // ---- layer 1 ----
    edge_fusedG<16><<<GG, 256, 0, stream>>>(x1, sperm32, ea_perm, eW1_1, eb1_1,
                                            eW2_1, eb2_1, off_all, msgbuf);
    gather_final<<<GG, 256, 0, stream>>>(x1, root1, bias1, off_all, msgbuf,
                                         mW1, mb1, mW2, mb2, out);
}

// Round 13
// 268.043 us; speedup vs baseline: 1.0539x; 1.0096x over previous
//
#include <hip/hip_runtime.h>
#include <hip/hip_fp16.h>

#define NN 50000
#define NE 800000
#define NBUCK 392          // buckets of 128 node-ids (7-bit local bins)
#define CAP 3584           // padded records per bucket (mean 2048, sigma~45)

__device__ __forceinline__ float sigm(float v) { return 1.0f / (1.0f + __expf(-v)); }

// ===========================================================================
// Sort-based CSR construction — R12 structure minus sort_count: scatter
// passes claim zero-based slots in PADDED bucket regions (cur* = exact
// totals as by-product); tiny 1-block scans densify afterwards. Downstream
// outputs (off_all / sperm32 / ea_perm) bit-identical to R12.
// ===========================================================================

// ---- generic 1-block exclusive scan of NBUCK totals -> base[0..NBUCK] ----
__global__ void scan1(const int* __restrict__ cnt, int* __restrict__ base)
{
    __shared__ int a[512];
    int t = threadIdx.x;
    a[t] = (t < NBUCK) ? cnt[t] : 0;
    __syncthreads();
#pragma unroll
    for (int dd = 1; dd < 512; dd <<= 1) {
        int v = (t >= dd) ? a[t - dd] : 0;
        __syncthreads();
        a[t] += v;
        __syncthreads();
    }
    int ex = (t > 0) ? a[t - 1] : 0;
    if (t <= NBUCK) base[t] = ex;
}

// ---- stage 1A: padded scatter {dlow:7|s:16|e:20}; curA -> exact totals ----
__global__ __launch_bounds__(256) void sort_scatterA(const int* __restrict__ ei,
                                                     int* __restrict__ curA,
                                                     unsigned long long* __restrict__ recA)
{
    __shared__ int lcnt[NBUCK];
    __shared__ int lofs[NBUCK];
    int t = threadIdx.x;
    for (int i = t; i < NBUCK; i += 256) lcnt[i] = 0;
    __syncthreads();
    int base = blockIdx.x * 4096;
#pragma unroll
    for (int r = 0; r < 16; ++r) {
        int e = base + r * 256 + t;
        if (e < NE) atomicAdd(&lcnt[ei[NE + e] >> 7], 1);
    }
    __syncthreads();
    for (int i = t; i < NBUCK; i += 256)
        lofs[i] = lcnt[i] ? atomicAdd(&curA[i], lcnt[i]) : 0;   // zero-based
    __syncthreads();
#pragma unroll
    for (int r = 0; r < 16; ++r) {
        int e = base + r * 256 + t;
        if (e < NE) {
            int s = ei[e], d = ei[NE + e];
            int p = atomicAdd(&lofs[d >> 7], 1);
            recA[(size_t)(d >> 7) * CAP + p] =
                  ((unsigned long long)(unsigned)(d & 127) << 36)
                | ((unsigned long long)(unsigned)s << 20)
                | (unsigned long long)(unsigned)e;
        }
    }
}

// ---- stage 2A+1B fused: per-dst-bucket counting sort -> dp + off_all[d];
//      padded scatter {slow:7|dp:20|e:20} into src-buckets (curB totals) ----
__global__ __launch_bounds__(256) void sort_localAB(const unsigned long long* __restrict__ recA,
                                                    const int* __restrict__ curA,
                                                    const int* __restrict__ baseA,
                                                    int* __restrict__ off_all,
                                                    int* __restrict__ curB,
                                                    unsigned long long* __restrict__ recB)
{
    __shared__ int c[128];
    __shared__ int live[128];
    __shared__ int lcnt[NBUCK];
    __shared__ int lofs[NBUCK];
    int t = threadIdx.x;
    int b = blockIdx.x;
    int n  = curA[b];                         // exact bucket count
    int lo = baseA[b];                        // dense base
    const unsigned long long* recs = recA + (size_t)b * CAP;
    if (t < 128) c[t] = 0;
    for (int i = t; i < NBUCK; i += 256) lcnt[i] = 0;
    __syncthreads();
    for (int i = t; i < n; i += 256) {
        unsigned long long rec = recs[i];
        atomicAdd(&c[(int)(rec >> 36) & 127], 1);       // d-bin
        atomicAdd(&lcnt[(int)(rec >> 27) & 511], 1);    // s>>7 bucket
    }
    __syncthreads();
#pragma unroll
    for (int dd = 1; dd < 128; dd <<= 1) {
        int v = (t >= dd && t < 128) ? c[t - dd] : 0;
        __syncthreads();
        if (t < 128) c[t] += v;
        __syncthreads();
    }
    if (t < 128) {
        int ex = (t > 0) ? c[t - 1] : 0;      // exclusive within-bucket prefix
        int d = (b << 7) + t;
        if (d <= NN) off_all[d] = lo + ex;    // d==NN -> b=390,t=80 -> NE
        live[t] = lo + ex;
    }
    __syncthreads();
    for (int i = t; i < NBUCK; i += 256)
        lofs[i] = lcnt[i] ? atomicAdd(&curB[i], lcnt[i]) : 0;   // zero-based
    __syncthreads();
    for (int i = t; i < n; i += 256) {
        unsigned long long rec = recs[i];
        int dp = atomicAdd(&live[(int)(rec >> 36) & 127], 1);
        int s  = (int)((rec >> 20) & 0xFFFFu);
        int p  = atomicAdd(&lofs[s >> 7], 1);
        recB[(size_t)(s >> 7) * CAP + p] =
              ((unsigned long long)(unsigned)(s & 127) << 40)
            | ((unsigned long long)(unsigned)dp << 20)
            | (rec & 0xFFFFFull);                        // e
    }
}

// ---- stage 2B: per-bucket sort by s&127 -> sperm32 + ea_perm + src offs ----
__global__ __launch_bounds__(256) void sort_localB(const unsigned long long* __restrict__ recB,
                                                   const int* __restrict__ curB,
                                                   const int* __restrict__ baseB,
                                                   const float4* __restrict__ ea4,
                                                   int* __restrict__ off_all,
                                                   unsigned* __restrict__ sperm32,
                                                   float4* __restrict__ ea_perm)
{
    __shared__ int c[128];
    __shared__ int live[128];
    int t = threadIdx.x;
    int b = blockIdx.x;
    int n  = curB[b];
    int lo = baseB[b];
    const unsigned long long* recs = recB + (size_t)b * CAP;
    if (t < 128) c[t] = 0;
    __syncthreads();
    for (int i = t; i < n; i += 256)
        atomicAdd(&c[(int)(recs[i] >> 40) & 127], 1);
    __syncthreads();
#pragma unroll
    for (int dd = 1; dd < 128; dd <<= 1) {
        int v = (t >= dd && t < 128) ? c[t - dd] : 0;
        __syncthreads();
        if (t < 128) c[t] += v;
        __syncthreads();
    }
    if (t < 128) {
        int ex = (t > 0) ? c[t - 1] : 0;
        int s = (b << 7) + t;
        if (s <= NN) off_all[NN + s] = NE + lo + ex;   // old off_all layout
        live[t] = lo + ex;
    }
    __syncthreads();
    for (int i = t; i < n; i += 256) {
        unsigned long long rec = recs[i];
        int k = (int)(rec >> 40) & 127;
        int pos = atomicAdd(&live[k], 1);
        unsigned sl = (unsigned)(k & 15);              // ((b<<7)+k)&15 == k&15
        unsigned dp = (unsigned)((rec >> 20) & 0xFFFFFu);
        sperm32[pos] = (sl << 20) | dp;
        ea_perm[pos] = ea4[rec & 0xFFFFFull];          // THE random gather, once
    }
}

// ===========================================================================
// edge_fusedG<DIN>: R10/R12-proven verbatim (44us, 64 VGPR, 38.9KB LDS).
// Reg-pack barrier-free phase 2: each thread owns its 16-ch row, 8x half2
// in regs, two 16B stores to the random dp row (same 32B sector).
// Phase 1: single-pass pad-17 LDS w2 staging.
// ===========================================================================
template<int DIN>
__global__ __launch_bounds__(256) void edge_fusedG(
        const float* __restrict__ xin,        // [NN][DIN]
        const unsigned* __restrict__ sperm32, // [NE] {sl:4|dp:20} src-sorted
        const float4* __restrict__ ea_perm,   // [NE] src-sorted edge attrs
        const float* __restrict__ eW1,        // [4][16]
        const float* __restrict__ eb1,        // [16]
        const float* __restrict__ eW2,        // [16][DIN*16]
        const float* __restrict__ eb2,        // [DIN*16]
        const int*   __restrict__ off_all,    // src CSR at off_all[NN+s]
        __half* __restrict__ msgbuf)          // [NE][16] fp16 dst-sorted rows
{
    __shared__ __align__(16) float4 w2L4[4 * DIN * 17]; // [(ob*DIN+i)*17+k]
    __shared__ __align__(16) float4 G4[16 * 69];        // [sl*69 + ob*17 + k]
    __shared__ __align__(16) float4 xbL[16 * 5];        // [sl*5 + ob] (pad 5)
    __shared__ __align__(16) float  xL[16 * DIN];
    __shared__ __align__(16) float  b2L[DIN * 16];
    __shared__ __align__(16) float4 w1t[16];
    __shared__ __align__(16) float  b1s[16];

    int tid = threadIdx.x;
    int nb  = blockIdx.x * 16;                // first src node of block
    if (tid < 16) {
        w1t[tid] = make_float4(eW1[tid], eW1[16 + tid], eW1[32 + tid], eW1[48 + tid]);
        b1s[tid] = eb1[tid];
    }
    {   // w2L4[(ob*DIN+i)*17 + k].c = eW2[k][i*16 + ob*4 + c]
        float* w2f = (float*)w2L4;
        for (int t = tid; t < 16 * DIN * 16; t += 256) {
            int k = t / (DIN * 16);
            int rem = t - k * DIN * 16;
            int i = rem >> 4, o = rem & 15;
            w2f[((((o >> 2) * DIN + i) * 17) + k) * 4 + (o & 3)] = eW2[t];
        }
    }
    for (int t = tid; t < DIN * 16; t += 256) b2L[t] = eb2[t];
    for (int t = tid; t < 16 * DIN; t += 256) xL[t] = xin[(size_t)nb * DIN + t];
    __syncthreads();

    // ---- phase 1: G + xb for 16 local nodes; thread (nl, k) ----
    {
        int nl = tid >> 4, k = tid & 15;
        const float* xrow = xL + nl * DIN;
#pragma unroll
        for (int ob = 0; ob < 4; ++ob) {
            float4 a4 = make_float4(0.f, 0.f, 0.f, 0.f);
#pragma unroll
            for (int i = 0; i < DIN; ++i) {
                float4 w = w2L4[(ob * DIN + i) * 17 + k];
                a4.x += xrow[i] * w.x; a4.y += xrow[i] * w.y;
                a4.z += xrow[i] * w.z; a4.w += xrow[i] * w.w;
            }
            G4[nl * 69 + ob * 17 + k] = a4;
        }
        if (k < 4) {
            int ob = k;
            const float4* b2v = (const float4*)b2L;
            float4 a4 = make_float4(0.f, 0.f, 0.f, 0.f);
#pragma unroll
            for (int i = 0; i < DIN; ++i) {
                float4 b = b2v[i * 4 + ob];
                a4.x += xrow[i] * b.x; a4.y += xrow[i] * b.y;
                a4.z += xrow[i] * b.z; a4.w += xrow[i] * b.w;
            }
            xbL[nl * 5 + ob] = a4;
        }
    }
    __syncthreads();

    // ---- phase 2: barrier-free edge loop; reg-pack + 32B random row store ----
    int eBeg = off_all[NN + nb] - NE;
    int eEnd = off_all[NN + nb + 16] - NE;
    for (int pos = eBeg + tid; pos < eEnd; pos += 256) {
        unsigned pk = sperm32[pos];
        int dp = (int)(pk & 0xFFFFFu);
        int sl = (int)(pk >> 20);
        float4 a = ea_perm[pos];

        float h[16];
#pragma unroll
        for (int j = 0; j < 16; ++j) {
            float4 w = w1t[j];
            float p = b1s[j] + a.x * w.x + a.y * w.y + a.z * w.z + a.w * w.w;
            h[j] = p * sigm(p);
        }
        float4 acc[4];
#pragma unroll
        for (int ob = 0; ob < 4; ++ob) acc[ob] = xbL[sl * 5 + ob];
#pragma unroll
        for (int k = 0; k < 16; ++k) {
            float hk = h[k];
#pragma unroll
            for (int ob = 0; ob < 4; ++ob) {
                float4 g = G4[sl * 69 + ob * 17 + k];
                acc[ob].x += hk * g.x; acc[ob].y += hk * g.y;
                acc[ob].z += hk * g.z; acc[ob].w += hk * g.w;
            }
        }
        __half2 h01 = __floats2half2_rn(acc[0].x, acc[0].y);
        __half2 h23 = __floats2half2_rn(acc[0].z, acc[0].w);
        __half2 h45 = __floats2half2_rn(acc[1].x, acc[1].y);
        __half2 h67 = __floats2half2_rn(acc[1].z, acc[1].w);
        __half2 h89 = __floats2half2_rn(acc[2].x, acc[2].y);
        __half2 hAB = __floats2half2_rn(acc[2].z, acc[2].w);
        __half2 hCD = __floats2half2_rn(acc[3].x, acc[3].y);
        __half2 hEF = __floats2half2_rn(acc[3].z, acc[3].w);
        uint4 w0 = make_uint4(*(unsigned*)&h01, *(unsigned*)&h23,
                              *(unsigned*)&h45, *(unsigned*)&h67);
        uint4 w1 = make_uint4(*(unsigned*)&h89, *(unsigned*)&hAB,
                              *(unsigned*)&hCD, *(unsigned*)&hEF);
        uint4* dst = (uint4*)(msgbuf + (size_t)dp * 16);   // random 32B row
        dst[0] = w0;
        dst[1] = w1;
    }
}

// ===========================================================================
// Gather helper (R5-proven): dst-sorted msgbuf -> streaming contiguous reads.
// ===========================================================================
__device__ __forceinline__ float gather_msg16(const __half* __restrict__ msgbuf,
                                              int s0, int e0, int tid)
{
    int half = (tid >> 3) & 1;
    int p    = tid & 7;
    float ax = 0.f, ay = 0.f;
    for (int j = s0 + half; j < e0; j += 2) {
        __half2 hv = *((const __half2*)(msgbuf + (size_t)j * 16) + p);
        float2 f = __half22float2(hv);
        ax += f.x; ay += f.y;
    }
    ax += __shfl_xor(ax, 8, 16);
    ay += __shfl_xor(ay, 8, 16);
    int ch = tid & 15;
    float vx = __shfl(ax, ch >> 1, 16);
    float vy = __shfl(ay, ch >> 1, 16);
    return (ch & 1) ? vy : vx;
}

__global__ __launch_bounds__(256) void gather_L0(
        const float* __restrict__ xin,    // [NN][8]
        const float* __restrict__ root,   // [8][16]
        const float* __restrict__ bias,   // [16]
        const int*   __restrict__ off_all,
        const __half* __restrict__ msgbuf,
        float* __restrict__ x1)           // [NN][16]
{
    __shared__ __align__(16) float rootL[8 * 16];
    __shared__ __align__(16) float biasL[16];
    int tid = threadIdx.x;
    if (tid < 128) rootL[tid] = root[tid];
    if (tid < 16) biasL[tid] = bias[tid];
    __syncthreads();

    int ch = tid & 15;
    int n  = blockIdx.x * 16 + (tid >> 4);
    int s0 = off_all[n], e0 = off_all[n + 1];

    float acc = gather_msg16(msgbuf, s0, e0, tid);
    float v = acc / fmaxf((float)(e0 - s0), 1.0f) + biasL[ch];
#pragma unroll
    for (int i = 0; i < 8; ++i)
        v += xin[(size_t)n * 8 + i] * rootL[i * 16 + ch];
    x1[(size_t)n * 16 + ch] = fmaxf(v, 0.f);
}

__global__ __launch_bounds__(256) void gather_final(
        const float* __restrict__ x1,     // [NN][16]
        const float* __restrict__ root,   // [16][16]
        const float* __restrict__ bias,   // [16]
        const int*   __restrict__ off_all,
        const __half* __restrict__ msgbuf,
        const float* __restrict__ mW1,    // [16][16]
        const float* __restrict__ mb1,    // [16]
        const float* __restrict__ mW2,    // [16]
        const float* __restrict__ mb2,    // [1]
        float* __restrict__ out)          // [NN]
{
    __shared__ __align__(16) float rootL[256];
    __shared__ __align__(16) float biasL[16];
    __shared__ __align__(16) float w1m[256];
    __shared__ __align__(16) float b1m[16];
    __shared__ __align__(16) float w2m[16];
    __shared__ float b2m;
    int tid = threadIdx.x;
    rootL[tid] = root[tid];
    w1m[tid] = mW1[tid];
    if (tid < 16) { biasL[tid] = bias[tid]; b1m[tid] = mb1[tid]; w2m[tid] = mW2[tid]; }
    if (tid == 0) b2m = mb2[0];
    __syncthreads();

    int ch = tid & 15;
    int n  = blockIdx.x * 16 + (tid >> 4);
    int s0 = off_all[n], e0 = off_all[n + 1];

    float acc = gather_msg16(msgbuf, s0, e0, tid);
    float v = acc / fmaxf((float)(e0 - s0), 1.0f) + biasL[ch];
#pragma unroll
    for (int i = 0; i < 16; ++i)
        v += x1[(size_t)n * 16 + i] * rootL[i * 16 + ch];
    v = fmaxf(v, 0.f);

    float z = b1m[ch];
#pragma unroll
    for (int o = 0; o < 16; ++o) {
        float vo = __shfl(v, o, 16);
        z += vo * w1m[o * 16 + ch];
    }
    float ss = z * sigm(z) * w2m[ch];
#pragma unroll
    for (int off = 8; off; off >>= 1) ss += __shfl_xor(ss, off, 16);
    if (ch == 0) out[n] = sigm(ss + b2m);
}

// ===========================================================================
// Host launch
// ===========================================================================
extern "C" void kernel_launch(void* const* d_in, const int* in_sizes, int n_in,
                              void* d_out, int out_size, void* d_ws, size_t ws_size,
                              hipStream_t stream) {
    const float* x     = (const float*)d_in[0];
    const int*   ei    = (const int*)  d_in[1];
    const float* ea    = (const float*)d_in[2];
    const float* eW1_0 = (const float*)d_in[3];
    const float* eb1_0 = (const float*)d_in[4];
    const float* eW2_0 = (const float*)d_in[5];
    const float* eb2_0 = (const float*)d_in[6];
    const float* root0 = (const float*)d_in[7];
    const float* bias0 = (const float*)d_in[8];
    const float* eW1_1 = (const float*)d_in[9];
    const float* eb1_1 = (const float*)d_in[10];
    const float* eW2_1 = (const float*)d_in[11];
    const float* eb2_1 = (const float*)d_in[12];
    const float* root1 = (const float*)d_in[13];
    const float* bias1 = (const float*)d_in[14];
    const float* mW1   = (const float*)d_in[15];
    const float* mb1   = (const float*)d_in[16];
    const float* mW2   = (const float*)d_in[17];
    const float* mb2   = (const float*)d_in[18];
    float* out = (float*)d_out;

    const int GG  = NN / 16;                 // 3125
    const int SBK = (NE + 4095) / 4096;      // 196 blocks for scatterA

    // ---- ws layout (4B words), peak ~10.52M words = 42.1 MB ----
    int* W = (int*)d_ws;
    int* off_all = W;                        // [0, 100004)
    int* curA    = W + 100004;               // 400
    int* curB    = W + 100404;               // 400
    int* baseA   = W + 100804;               // 400 (393 used)
    int* baseB   = W + 101204;               // 400 -> pad to 102400
    unsigned* sperm32 = (unsigned*)(W + 102400);           // NE u32
    float4* ea_perm   = (float4*)(W + 902400);             // NE float4 (16B-aligned)
    float*  x1        = (float*)(W + 4102400);             // [NN][16]
    __half* msgbuf    = (__half*)(W + 4902400);            // [NE][16] fp16, dst order
    // padded sort scratch overlaid on msgbuf region (dead before edge kernels):
    unsigned long long* recA = (unsigned long long*)(W + 4902400); // 392*CAP u64
    unsigned long long* recB = (unsigned long long*)(W + 7712256); // 392*CAP u64
    // recB ends at 7712256 + 2809856 = 10522112 words < R12's 11.3M peak

    hipMemsetAsync(curA, 0, 800 * sizeof(int), stream);   // curA + curB
    sort_scatterA<<<SBK,  256, 0, stream>>>(ei, curA, recA);
    scan1        <<<1,    512, 0, stream>>>(curA, baseA);
    sort_localAB <<<NBUCK,256, 0, stream>>>(recA, curA, baseA, off_all, curB, recB);
    scan1        <<<1,    512, 0, stream>>>(curB, baseB);
    sort_localB  <<<NBUCK,256, 0, stream>>>(recB, curB, baseB, (const float4*)ea,
                                            off_all, sperm32, ea_perm);

    // ---- layer 0 ----
    edge_fusedG<8><<<GG, 256, 0, stream>>>(x, sperm32, ea_perm, eW1_0, eb1_0,
                                           eW2_0, eb2_0, off_all, msgbuf);
    gather_L0<<<GG, 256, 0, stream>>>(x, root0, bias0, off_all, msgbuf, x1);

    // ---- layer 1 ----
    edge_fusedG<16><<<GG, 256, 0, stream>>>(x1, sperm32, ea_perm, eW1_1, eb1_1,
                                            eW2_1, eb2_1, off_all, msgbuf);
    gather_final<<<GG, 256, 0, stream>>>(x1, root1, bias1, off_all, msgbuf,
                                         mW1, mb1, mW2, mb2, out);
}